// Round 3
// baseline (518.452 us; speedup 1.0000x reference)
//
#include <hip/hip_runtime.h>
#include <cmath>

#define NHEADS 32
#define DIM 128
#define SPLITS 16
#define TILE 32
#define KSPLIT 8
#define QKV_N 4352
#define HID 4096

// C[64,N] += A[64,K] @ W[K,N], split-K partials. grid=(N/64, KSPLIT), block=256
__global__ __launch_bounds__(256) void gemm64_part(
    const float* __restrict__ A, const float* __restrict__ W,
    float* __restrict__ P, int N, int K)
{
  __shared__ float As[32][64];   // As[k][m] (transposed)
  __shared__ float Ws[32][68];   // Ws[k][n], padded
  const int t = threadIdx.x;
  const int n0 = blockIdx.x * 64;
  const int KS = K / KSPLIT;
  const int kbase = blockIdx.y * KS;
  const int tx = t & 15, ty = t >> 4;
  float acc[4][4] = {{0.f, 0.f, 0.f, 0.f}, {0.f, 0.f, 0.f, 0.f},
                     {0.f, 0.f, 0.f, 0.f}, {0.f, 0.f, 0.f, 0.f}};
  for (int kc = 0; kc < KS; kc += 32) {
    {
      int idx = t;
#pragma unroll
      for (int it = 0; it < 2; ++it, idx += 256) {
        const int m = idx >> 3, kq = idx & 7;
        const float4 av = *(const float4*)(A + (size_t)m * K + kbase + kc + kq * 4);
        As[kq * 4 + 0][m] = av.x; As[kq * 4 + 1][m] = av.y;
        As[kq * 4 + 2][m] = av.z; As[kq * 4 + 3][m] = av.w;
      }
      idx = t;
#pragma unroll
      for (int it = 0; it < 2; ++it, idx += 256) {
        const int kk = idx >> 4, nq = idx & 15;
        const float4 wv = *(const float4*)(W + (size_t)(kbase + kc + kk) * N + n0 + nq * 4);
        *(float4*)&Ws[kk][nq * 4] = wv;
      }
    }
    __syncthreads();
#pragma unroll 8
    for (int kk = 0; kk < 32; ++kk) {
      const float4 a = *(const float4*)&As[kk][ty * 4];
      const float4 w = *(const float4*)&Ws[kk][tx * 4];
      acc[0][0] += a.x * w.x; acc[0][1] += a.x * w.y; acc[0][2] += a.x * w.z; acc[0][3] += a.x * w.w;
      acc[1][0] += a.y * w.x; acc[1][1] += a.y * w.y; acc[1][2] += a.y * w.z; acc[1][3] += a.y * w.w;
      acc[2][0] += a.z * w.x; acc[2][1] += a.z * w.y; acc[2][2] += a.z * w.z; acc[2][3] += a.z * w.w;
      acc[3][0] += a.w * w.x; acc[3][1] += a.w * w.y; acc[3][2] += a.w * w.z; acc[3][3] += a.w * w.w;
    }
    __syncthreads();
  }
  float* base = P + (size_t)blockIdx.y * 64 * N + (size_t)(ty * 4) * N + n0 + tx * 4;
#pragma unroll
  for (int i = 0; i < 4; ++i) {
    const float4 v = make_float4(acc[i][0], acc[i][1], acc[i][2], acc[i][3]);
    *(float4*)(base + (size_t)i * N) = v;
  }
}

__global__ __launch_bounds__(256) void reduce_parts(
    const float* __restrict__ P, float* __restrict__ C, int total)
{
  const int i = (blockIdx.x * 256 + threadIdx.x) * 4;
  if (i >= total) return;
  float4 s = *(const float4*)(P + i);
#pragma unroll
  for (int k = 1; k < KSPLIT; ++k) {
    const float4 v = *(const float4*)(P + (size_t)k * total + i);
    s.x += v.x; s.y += v.y; s.z += v.z; s.w += v.w;
  }
  *(float4*)(C + i) = s;
}

// RoPE in place on q (32 heads) and k row of qkv. grid=64, block=256
__global__ __launch_bounds__(256) void rope_kernel(
    float* __restrict__ qkv, const int* __restrict__ positions)
{
  const int b = blockIdx.x;
  float* row = qkv + (size_t)b * QKV_N;
  const float pos = (float)positions[b];
  for (int it = threadIdx.x; it < 33 * 64; it += 256) {
    const int r = it >> 6, i = it & 63;
    float* x = row + (r < 32 ? r * DIM : HID);
    const float ex = (float)(2 * i) * (1.0f / 128.0f);
    const float inv = 1.0f / powf(10000.0f, ex);
    const float ang = pos * inv;
    const float c = cosf(ang), sn = sinf(ang);
    const float x1 = x[i], x2 = x[i + 64];
    x[i]      = x1 * c - x2 * sn;
    x[i + 64] = x2 * c + x1 * sn;
  }
}

// Flash-decoding attention, LDS-resident tiles, double-buffered.
// grid=(64, SPLITS), block=256 (4 waves x 8 heads).
// Scores: lane = (pos = lane&31, dim-half = lane>>5). PV: lane = (pos parity, 4-dim group).
__global__ __launch_bounds__(256) void attn_kernel(
    const float* __restrict__ qkv,
    const float* __restrict__ k_cache, const float* __restrict__ v_cache,
    const int* __restrict__ block_tables, const int* __restrict__ context_lens,
    float* __restrict__ pm, float* __restrict__ pl, float* __restrict__ pacc)
{
  const int b = blockIdx.x, s = blockIdx.y;
  const int t = threadIdx.x;
  const int w = t >> 6, lane = t & 63;
  const int ctx = context_lens[b];
  const int pos = ctx - 1;
  const int chunk = (ctx + SPLITS - 1) / SPLITS;
  const int start = s * chunk;
  const int end = min(start + chunk, ctx);

  __shared__ float qs[NHEADS][DIM];           // 16 KB
  __shared__ float Ks[2][TILE][DIM + 4];      // 33 KB (dbuf)
  __shared__ float Vs[2][TILE][DIM + 4];      // 33 KB (dbuf)
  __shared__ float ps[4][8][TILE];            // 4 KB (per-wave)

  const float* qbase = qkv + (size_t)b * QKV_N;
#pragma unroll
  for (int i = 0; i < 4; ++i) {
    const int idx = t + i * 256;
    ((float4*)qs)[idx] = ((const float4*)qbase)[idx];
  }

  const int h0 = w * 8;
  const int srow = t >> 3, scol = t & 7;     // staging: row 0..31, float4 col group 0..7
  const float scale = 0.08838834764831845f;  // 1/sqrt(128)

  float mh[8], lh[8], acc[8][4];
#pragma unroll
  for (int h = 0; h < 8; ++h) {
    mh[h] = -1e30f; lh[h] = 0.f;
    acc[h][0] = 0.f; acc[h][1] = 0.f; acc[h][2] = 0.f; acc[h][3] = 0.f;
  }

  const int nt = (end > start) ? ((end - start + TILE - 1) / TILE) : 0;
  float4 kreg[4], vreg[4];

#define LOAD_TILE(T0)                                                          \
  {                                                                            \
    int gpos = (T0) + srow;                                                    \
    if (gpos > pos) gpos = pos; /* clamp: masked later, keeps addr valid */    \
    const float *kp, *vp;                                                      \
    if (gpos == pos) { kp = qbase + HID; vp = qbase + HID + DIM; }             \
    else {                                                                     \
      const int blk = block_tables[b * 256 + (gpos >> 4)];                     \
      const size_t cidx = ((size_t)blk * 16 + (gpos & 15)) * DIM;              \
      kp = k_cache + cidx; vp = v_cache + cidx;                                \
    }                                                                          \
    _Pragma("unroll")                                                          \
    for (int j = 0; j < 4; ++j) {                                              \
      kreg[j] = ((const float4*)kp)[scol + j * 8];                             \
      vreg[j] = ((const float4*)vp)[scol + j * 8];                             \
    }                                                                          \
  }

#define WRITE_TILE(BUF)                                                        \
  {                                                                            \
    _Pragma("unroll")                                                          \
    for (int j = 0; j < 4; ++j) {                                              \
      *(float4*)&Ks[BUF][srow][(scol + j * 8) * 4] = kreg[j];                  \
      *(float4*)&Vs[BUF][srow][(scol + j * 8) * 4] = vreg[j];                  \
    }                                                                          \
  }

  if (nt > 0) {
    LOAD_TILE(start);
    WRITE_TILE(0);
    __syncthreads();

    for (int it = 0; it < nt; ++it) {
      const int t0 = start + it * TILE;
      const int cur = it & 1;
      const bool pre = (it + 1 < nt);
      if (pre) LOAD_TILE(t0 + TILE);

      // ---- scores: sc[h] = partial dot over this lane's dim-half ----
      const int p32 = lane & 31;
      const int hp = (lane >> 5) * 64;
      float sc[8] = {0.f, 0.f, 0.f, 0.f, 0.f, 0.f, 0.f, 0.f};
#pragma unroll
      for (int kk = 0; kk < 16; ++kk) {
        const float4 kv = *(const float4*)&Ks[cur][p32][hp + kk * 4];
#pragma unroll
        for (int h = 0; h < 8; ++h) {
          const float4 qv = *(const float4*)&qs[h0 + h][hp + kk * 4];
          sc[h] += qv.x * kv.x + qv.y * kv.y + qv.z * kv.z + qv.w * kv.w;
        }
      }
      const bool valid = (t0 + p32) < end;
#pragma unroll
      for (int h = 0; h < 8; ++h) {
        float sv = sc[h] + __shfl_xor(sc[h], 32);        // combine dim halves
        sv = valid ? sv * scale : -1e30f;
        float tm = sv;                                    // max over 32-pos group
#pragma unroll
        for (int o = 16; o > 0; o >>= 1) tm = fmaxf(tm, __shfl_xor(tm, o));
        const float nm = fmaxf(mh[h], tm);
        const float corr = __expf(mh[h] - nm);
        const float pv = __expf(sv - nm);
        float sum = pv;
#pragma unroll
        for (int o = 16; o > 0; o >>= 1) sum += __shfl_xor(sum, o);
        lh[h] = lh[h] * corr + sum;
        mh[h] = nm;
        acc[h][0] *= corr; acc[h][1] *= corr; acc[h][2] *= corr; acc[h][3] *= corr;
        if (lane < 32) ps[w][h][lane] = pv;
      }

      // ---- PV: 2 positions per step, lane covers 4 dims ----
      const int dg = (lane & 31) * 4;       // dim group
      const int half = lane >> 5;           // position parity
#pragma unroll
      for (int st = 0; st < 16; ++st) {
        const int l = st * 2 + half;
        const float4 vv = *(const float4*)&Vs[cur][l][dg];
#pragma unroll
        for (int h = 0; h < 8; ++h) {
          const float pb = ps[w][h][l];
          acc[h][0] += pb * vv.x; acc[h][1] += pb * vv.y;
          acc[h][2] += pb * vv.z; acc[h][3] += pb * vv.w;
        }
      }

      if (pre) {
        WRITE_TILE(cur ^ 1);
        __syncthreads();
      }
    }
  }

  // combine position-parity halves: lane and lane^32 hold disjoint partial sums
#pragma unroll
  for (int h = 0; h < 8; ++h) {
    acc[h][0] += __shfl_xor(acc[h][0], 32);
    acc[h][1] += __shfl_xor(acc[h][1], 32);
    acc[h][2] += __shfl_xor(acc[h][2], 32);
    acc[h][3] += __shfl_xor(acc[h][3], 32);
  }

  const size_t base = ((size_t)(b * SPLITS + s) * NHEADS + h0);
#pragma unroll
  for (int h = 0; h < 8; ++h) {
    if (lane == 0) { pm[base + h] = mh[h]; pl[base + h] = lh[h]; }
    if (lane < 32) {
      *(float4*)&pacc[(base + h) * DIM + lane * 4] =
          make_float4(acc[h][0], acc[h][1], acc[h][2], acc[h][3]);
    }
  }
#undef LOAD_TILE
#undef WRITE_TILE
}

// combine partials -> attn[b][h*128+d]. grid=2048, block=128
__global__ __launch_bounds__(128) void combine_kernel(
    const float* __restrict__ pm, const float* __restrict__ pl,
    const float* __restrict__ pacc, float* __restrict__ attn)
{
  const int bh = blockIdx.x;
  const int b = bh >> 5, h = bh & 31;
  const int d = threadIdx.x;
  float ms[SPLITS], ls[SPLITS];
  float M = -1e30f;
#pragma unroll
  for (int s = 0; s < SPLITS; ++s) {
    ms[s] = pm[(size_t)(b * SPLITS + s) * NHEADS + h];
    ls[s] = pl[(size_t)(b * SPLITS + s) * NHEADS + h];
    M = fmaxf(M, ms[s]);
  }
  float L = 0.f, o = 0.f;
#pragma unroll
  for (int s = 0; s < SPLITS; ++s) {
    const float wgt = __expf(ms[s] - M);
    L += ls[s] * wgt;
    o += wgt * pacc[((size_t)(b * SPLITS + s) * NHEADS + h) * DIM + d];
  }
  attn[(size_t)b * HID + h * DIM + d] = o / L;
}

extern "C" void kernel_launch(void* const* d_in, const int* in_sizes, int n_in,
                              void* d_out, int out_size, void* d_ws, size_t ws_size,
                              hipStream_t stream) {
  const float* hidden   = (const float*)d_in[0];
  const float* wqkv     = (const float*)d_in[1];
  const float* wdense   = (const float*)d_in[2];
  const float* k_cache  = (const float*)d_in[3];
  const float* v_cache  = (const float*)d_in[4];
  const int* positions    = (const int*)d_in[5];   // integer inputs arrive as int32
  const int* block_tables = (const int*)d_in[6];
  const int* context_lens = (const int*)d_in[7];
  float* out = (float*)d_out;

  float* qkv  = (float*)d_ws;                 // 64*4352
  float* attn = qkv + 64 * QKV_N;             // 64*4096
  // union region: gp (GEMM partials, lifetime before attn / after combine)
  // aliases pacc/pm/pl (lifetime attn->combine). Sizes: gp = 8*64*4352 = 2.23M,
  // pacc+pm+pl = 64*16*32*128 + 2*64*16*32 = 4.26M floats -> region 4.26M.
  float* un   = attn + 64 * HID;
  float* gp   = un;
  float* pacc = un;
  float* pm   = pacc + (size_t)64 * SPLITS * NHEADS * DIM;
  float* pl   = pm + 64 * SPLITS * NHEADS;

  // 1) qkv = hidden @ wqkv
  gemm64_part<<<dim3(QKV_N / 64, KSPLIT), 256, 0, stream>>>(hidden, wqkv, gp, QKV_N, HID);
  reduce_parts<<<(64 * QKV_N) / 1024, 256, 0, stream>>>(gp, qkv, 64 * QKV_N);
  // 2) RoPE on q and k
  rope_kernel<<<64, 256, 0, stream>>>(qkv, positions);
  // 3) attention (flash-decoding, SPLITS context chunks)
  attn_kernel<<<dim3(64, SPLITS), 256, 0, stream>>>(qkv, k_cache, v_cache,
                                                    block_tables, context_lens, pm, pl, pacc);
  combine_kernel<<<64 * NHEADS, 128, 0, stream>>>(pm, pl, pacc, attn);
  // 4) out = attn @ wdense
  gemm64_part<<<dim3(HID / 64, KSPLIT), 256, 0, stream>>>(attn, wdense, gp, HID, HID);
  reduce_parts<<<(64 * HID) / 1024, 256, 0, stream>>>(gp, out, 64 * HID);
}